// Round 2
// baseline (827.598 us; speedup 1.0000x reference)
//
#include <hip/hip_runtime.h>
#include <hip/hip_bf16.h>

#define N_NODES 8192
#define HID 64

typedef __attribute__((ext_vector_type(8))) short bf16x8;
typedef __attribute__((ext_vector_type(4))) float f32x4;

// ---------------- degree / normalization ----------------
__global__ void k_deg_init(int* __restrict__ deg) {
    int i = blockIdx.x * 256 + threadIdx.x;
    deg[i] = 1;  // self loop
}

__global__ void k_deg_count(const int* __restrict__ dst, int* __restrict__ deg, int E) {
    int e = blockIdx.x * 256 + threadIdx.x;
    if (e < E) atomicAdd(&deg[dst[e]], 1);
}

__global__ void k_dinv(const int* __restrict__ deg, float* __restrict__ dinv) {
    int i = blockIdx.x * 256 + threadIdx.x;
    dinv[i] = rsqrtf((float)deg[i]);
}

// ---------------- dense linear:  Y[8192,64] = X[8192,K] @ W[K,64] ----------------
__global__ void __launch_bounds__(256) k_gemm(const float* __restrict__ X,
                                              const float* __restrict__ W,
                                              float* __restrict__ Y, int K) {
    const int col  = threadIdx.x & 63;
    const int wv   = threadIdx.x >> 6;            // wave id 0..3
    const int row0 = blockIdx.x * 16 + wv * 4;    // 4 rows per thread
    float a0 = 0.f, a1 = 0.f, a2 = 0.f, a3 = 0.f;
    const float* x0 = X + (size_t)row0 * K;
    for (int k = 0; k < K; ++k) {
        float w = W[k * 64 + col];
        a0 += x0[k] * w;
        a1 += x0[K + k] * w;
        a2 += x0[2 * K + k] * w;
        a3 += x0[3 * K + k] * w;
    }
    size_t o = (size_t)row0 * 64 + col;
    Y[o] = a0; Y[o + 64] = a1; Y[o + 128] = a2; Y[o + 192] = a3;
}

// ---------------- aggregation ----------------
// self-loop term: agg[i][c] = H[i][c] * dinv[i]^2
__global__ void k_agg_init(const float* __restrict__ H, const float* __restrict__ dinv,
                           float* __restrict__ agg) {
    int i = blockIdx.x * 256 + threadIdx.x;
    int row = i >> 6;
    float di = dinv[row];
    agg[i] = H[i] * di * di;
}

// edge scatter: 16 threads per edge, float4 per thread
__global__ void k_agg_edges(const int* __restrict__ src, const int* __restrict__ dst,
                            const float* __restrict__ dinv, const float* __restrict__ H,
                            float* __restrict__ agg, int E) {
    int gid = blockIdx.x * 256 + threadIdx.x;
    int e = gid >> 4, q = gid & 15;
    if (e >= E) return;
    int s = src[e], d = dst[e];
    float w = dinv[s] * dinv[d];
    float4 v = ((const float4*)(H + (size_t)s * 64))[q];
    float* out = agg + (size_t)d * 64 + q * 4;
    atomicAdd(out + 0, v.x * w);
    atomicAdd(out + 1, v.y * w);
    atomicAdd(out + 2, v.z * w);
    atomicAdd(out + 3, v.w * w);
}

__global__ void k_bias_relu(float* __restrict__ buf, const float* __restrict__ b) {
    int i = blockIdx.x * 256 + threadIdx.x;
    float v = buf[i] + b[i & 63];
    buf[i] = v > 0.f ? v : 0.f;
}

__global__ void k_bias_relu_bf16(const float* __restrict__ buf, const float* __restrict__ b,
                                 __hip_bfloat16* __restrict__ out) {
    int i = blockIdx.x * 256 + threadIdx.x;
    float v = buf[i] + b[i & 63];
    out[i] = __float2bfloat16(v > 0.f ? v : 0.f);
}

// ---------------- sim = sigmoid(h @ h^T), bf16 MFMA ----------------
// block = 256 thr (4 waves), block tile 128x128, wave tile 64x64 (4x4 MFMA tiles)
__global__ void __launch_bounds__(256) k_sim(const short* __restrict__ Hb,
                                             float* __restrict__ out) {
    const int lane = threadIdx.x & 63;
    const int wv   = threadIdx.x >> 6;
    const int br = blockIdx.y * 128 + (wv >> 1) * 64;
    const int bc = blockIdx.x * 128 + (wv & 1) * 64;
    const int lr = lane & 15;   // row/col within 16
    const int kg = lane >> 4;   // k-group (8 contiguous bf16)

    bf16x8 a[4][2], b[4][2];
#pragma unroll
    for (int t = 0; t < 4; ++t)
#pragma unroll
        for (int kk = 0; kk < 2; ++kk) {
            a[t][kk] = *(const bf16x8*)(Hb + (size_t)(br + t * 16 + lr) * 64 + kk * 32 + kg * 8);
            b[t][kk] = *(const bf16x8*)(Hb + (size_t)(bc + t * 16 + lr) * 64 + kk * 32 + kg * 8);
        }

    f32x4 acc[4][4] = {};
#pragma unroll
    for (int i = 0; i < 4; ++i)
#pragma unroll
        for (int j = 0; j < 4; ++j) {
            acc[i][j] = __builtin_amdgcn_mfma_f32_16x16x32_bf16(a[i][0], b[j][0], acc[i][j], 0, 0, 0);
            acc[i][j] = __builtin_amdgcn_mfma_f32_16x16x32_bf16(a[i][1], b[j][1], acc[i][j], 0, 0, 0);
        }

#pragma unroll
    for (int i = 0; i < 4; ++i)
#pragma unroll
        for (int j = 0; j < 4; ++j)
#pragma unroll
            for (int r = 0; r < 4; ++r) {
                int row = br + i * 16 + kg * 4 + r;
                int col = bc + j * 16 + lr;
                float s = acc[i][j][r];
                out[(size_t)row * N_NODES + col] = 1.0f / (1.0f + __expf(-s));
            }
}

extern "C" void kernel_launch(void* const* d_in, const int* in_sizes, int n_in,
                              void* d_out, int out_size, void* d_ws, size_t ws_size,
                              hipStream_t stream) {
    const float* x  = (const float*)d_in[0];
    const int*   ei = (const int*)d_in[1];
    const float* W1 = (const float*)d_in[2];
    const float* b1 = (const float*)d_in[3];
    const float* W2 = (const float*)d_in[4];
    const float* b2 = (const float*)d_in[5];
    const int E = in_sizes[1] / 2;
    const int* src = ei;
    const int* dst = ei + E;

    char* ws = (char*)d_ws;
    int*   deg  = (int*)ws;                                      // 32 KB
    float* dinv = (float*)(ws + 32 * 1024);                      // 32 KB
    float* A    = (float*)(ws + 64 * 1024);                      // 2 MB (hlin / hlin2)
    float* B    = (float*)(ws + 64 * 1024 + 2 * 1024 * 1024);    // 2 MB (agg / h1 / agg2)
    __hip_bfloat16* h2b = (__hip_bfloat16*)(ws + 64 * 1024 + 4 * 1024 * 1024);  // 1 MB

    const int NB = N_NODES / 256;           // 32
    const int EB = (E + 255) / 256;         // 1024
    const int ELEMS = N_NODES * HID / 256;  // 2048

    k_deg_init<<<NB, 256, 0, stream>>>(deg);
    k_deg_count<<<EB, 256, 0, stream>>>(dst, deg, E);
    k_dinv<<<NB, 256, 0, stream>>>(deg, dinv);

    // layer 1
    k_gemm<<<N_NODES / 16, 256, 0, stream>>>(x, W1, A, 128);
    k_agg_init<<<ELEMS, 256, 0, stream>>>(A, dinv, B);
    k_agg_edges<<<(E * 16) / 256, 256, 0, stream>>>(src, dst, dinv, A, B, E);
    k_bias_relu<<<ELEMS, 256, 0, stream>>>(B, b1);

    // layer 2
    k_gemm<<<N_NODES / 16, 256, 0, stream>>>(B, W2, A, 64);
    k_agg_init<<<ELEMS, 256, 0, stream>>>(A, dinv, B);
    k_agg_edges<<<(E * 16) / 256, 256, 0, stream>>>(src, dst, dinv, A, B, E);
    k_bias_relu_bf16<<<ELEMS, 256, 0, stream>>>(B, b2, h2b);

    // sim = sigmoid(h2 @ h2^T)
    dim3 g(N_NODES / 128, N_NODES / 128);
    k_sim<<<g, 256, 0, stream>>>((const short*)h2b, (float*)d_out);
}

// Round 8
// 416.112 us; speedup vs baseline: 1.9889x; 1.9889x over previous
//
#include <hip/hip_runtime.h>
#include <hip/hip_bf16.h>

#define N_NODES 8192
#define HID 64

typedef __attribute__((ext_vector_type(8))) short bf16x8;
typedef __attribute__((ext_vector_type(4))) float f32x4;

// ---------------- degree / normalization ----------------
// deg (int) and dinv (float) SHARE one 32KB buffer; k_dinv_inplace converts
// int->rsqrt(float) in place, and runs AFTER k_scan (which needs integer deg).
__global__ void k_deg_init(int* __restrict__ deg) {
    int i = blockIdx.x * 256 + threadIdx.x;
    deg[i] = 1;  // self loop
}

__global__ void k_deg_count(const int* __restrict__ dst, int* __restrict__ deg, int E) {
    int e = blockIdx.x * 256 + threadIdx.x;
    if (e < E) atomicAdd(&deg[dst[e]], 1);
}

__global__ void k_dinv_inplace(int* __restrict__ degdinv) {
    int i = blockIdx.x * 256 + threadIdx.x;
    float d = (float)degdinv[i];
    ((float*)degdinv)[i] = rsqrtf(d);
}

// ---------------- CSR build (once; reused by both layers) ----------------
// exclusive scan of edge-degrees (deg-1) over 8192 nodes, single block.
// off has EXACTLY 8192 ints; off[8192] is NOT stored (gather uses E for the
// last node) -- storing it was the R7 crash (overflowed into cursor[0]).
__global__ void __launch_bounds__(1024) k_scan(const int* __restrict__ deg,
                                               int* __restrict__ off,
                                               int* __restrict__ cursor) {
    __shared__ int s[1024];
    const int t = threadIdx.x;
    int v[8];
    int sum = 0;
    const int base = t * 8;
#pragma unroll
    for (int j = 0; j < 8; ++j) { v[j] = deg[base + j] - 1; sum += v[j]; }
    s[t] = sum;
    __syncthreads();
    for (int d = 1; d < 1024; d <<= 1) {
        int x = (t >= d) ? s[t - d] : 0;
        __syncthreads();
        s[t] += x;
        __syncthreads();
    }
    int ex = s[t] - sum;  // exclusive prefix
#pragma unroll
    for (int j = 0; j < 8; ++j) {
        off[base + j] = ex;
        cursor[base + j] = ex;
        ex += v[j];
    }
}

// bucket edges by dst; store src only (norm factored into gemm epilogue/gather)
__global__ void k_fill(const int* __restrict__ src, const int* __restrict__ dst,
                       int* __restrict__ cursor, int* __restrict__ csr, int E) {
    int e = blockIdx.x * 256 + threadIdx.x;
    if (e >= E) return;
    int pos = atomicAdd(&cursor[dst[e]], 1);
    csr[pos] = src[e];
}

// ---------------- dense linear + row scale:  Y[r] = dinv[r] * (X @ W)[r] ----
__global__ void __launch_bounds__(256) k_gemm(const float* __restrict__ X,
                                              const float* __restrict__ W,
                                              const float* __restrict__ dinv,
                                              float* __restrict__ Y, int K) {
    const int col  = threadIdx.x & 63;
    const int wv   = threadIdx.x >> 6;            // wave id 0..3
    const int row0 = blockIdx.x * 16 + wv * 4;    // 4 rows per thread
    float a0 = 0.f, a1 = 0.f, a2 = 0.f, a3 = 0.f;
    const float* x0 = X + (size_t)row0 * K;
    for (int k = 0; k < K; ++k) {
        float w = W[k * 64 + col];
        a0 += x0[k] * w;
        a1 += x0[K + k] * w;
        a2 += x0[2 * K + k] * w;
        a3 += x0[3 * K + k] * w;
    }
    size_t o = (size_t)row0 * 64 + col;
    Y[o]       = a0 * dinv[row0];
    Y[o + 64]  = a1 * dinv[row0 + 1];
    Y[o + 128] = a2 * dinv[row0 + 2];
    Y[o + 192] = a3 * dinv[row0 + 3];
}

// ---------------- gather aggregation + bias + relu (fused) ----------------
// Hs[r] = dinv[r]*(XW)[r] already scaled. agg[d] = dinv[d]*(Hs[d] + sum Hs[src]).
// one wave per node, lane = channel. MODE 0: write float. MODE 1: write bf16.
template <int MODE>
__global__ void __launch_bounds__(256) k_gather(const float* __restrict__ Hs,
                                                const float* __restrict__ dinv,
                                                const int* __restrict__ off,
                                                const int* __restrict__ csr,
                                                const float* __restrict__ bias,
                                                float* __restrict__ outf,
                                                __hip_bfloat16* __restrict__ outb,
                                                int E) {
    const int node = blockIdx.x * 4 + (threadIdx.x >> 6);
    const int lane = threadIdx.x & 63;
    float acc = Hs[(size_t)node * 64 + lane];  // self-loop term (pre-scaled)
    int k = off[node];
    const int end = (node == N_NODES - 1) ? E : off[node + 1];
    for (; k + 1 < end; k += 2) {  // unroll-2: two independent load chains
        int s0 = csr[k];
        int s1 = csr[k + 1];
        float h0 = Hs[(size_t)s0 * 64 + lane];
        float h1 = Hs[(size_t)s1 * 64 + lane];
        acc += h0;
        acc += h1;
    }
    if (k < end) acc += Hs[(size_t)csr[k] * 64 + lane];
    float v = dinv[node] * acc + bias[lane];
    v = v > 0.f ? v : 0.f;
    if (MODE == 0) outf[(size_t)node * 64 + lane] = v;
    else           outb[(size_t)node * 64 + lane] = __float2bfloat16(v);
}

// ---------------- sim = sigmoid(h @ h^T), bf16 MFMA ----------------
// block = 256 thr (4 waves), block tile 128x128, wave tile 64x64 (4x4 MFMA tiles)
__global__ void __launch_bounds__(256) k_sim(const short* __restrict__ Hb,
                                             float* __restrict__ out) {
    const int lane = threadIdx.x & 63;
    const int wv   = threadIdx.x >> 6;
    const int br = blockIdx.y * 128 + (wv >> 1) * 64;
    const int bc = blockIdx.x * 128 + (wv & 1) * 64;
    const int lr = lane & 15;   // row/col within 16
    const int kg = lane >> 4;   // k-group (8 contiguous bf16)

    bf16x8 a[4][2], b[4][2];
#pragma unroll
    for (int t = 0; t < 4; ++t)
#pragma unroll
        for (int kk = 0; kk < 2; ++kk) {
            a[t][kk] = *(const bf16x8*)(Hb + (size_t)(br + t * 16 + lr) * 64 + kk * 32 + kg * 8);
            b[t][kk] = *(const bf16x8*)(Hb + (size_t)(bc + t * 16 + lr) * 64 + kk * 32 + kg * 8);
        }

    f32x4 acc[4][4] = {};
#pragma unroll
    for (int i = 0; i < 4; ++i)
#pragma unroll
        for (int j = 0; j < 4; ++j) {
            acc[i][j] = __builtin_amdgcn_mfma_f32_16x16x32_bf16(a[i][0], b[j][0], acc[i][j], 0, 0, 0);
            acc[i][j] = __builtin_amdgcn_mfma_f32_16x16x32_bf16(a[i][1], b[j][1], acc[i][j], 0, 0, 0);
        }

#pragma unroll
    for (int i = 0; i < 4; ++i)
#pragma unroll
        for (int j = 0; j < 4; ++j)
#pragma unroll
            for (int r = 0; r < 4; ++r) {
                int row = br + i * 16 + kg * 4 + r;
                int col = bc + j * 16 + lr;
                float s = acc[i][j][r];
                out[(size_t)row * N_NODES + col] = 1.0f / (1.0f + __expf(-s));
            }
}

extern "C" void kernel_launch(void* const* d_in, const int* in_sizes, int n_in,
                              void* d_out, int out_size, void* d_ws, size_t ws_size,
                              hipStream_t stream) {
    const float* x  = (const float*)d_in[0];
    const int*   ei = (const int*)d_in[1];
    const float* W1 = (const float*)d_in[2];
    const float* b1 = (const float*)d_in[3];
    const float* W2 = (const float*)d_in[4];
    const float* b2 = (const float*)d_in[5];
    const int E = in_sizes[1] / 2;
    const int* src = ei;
    const int* dst = ei + E;

    // Workspace layout -- total 64KB + 5MB = 5,308,416 B (== R2-proven usage).
    //   degdinv : 0..32K      (int deg, converted in-place to float rsqrt)
    //   off     : 32K..64K    (8192 ints exactly; off[8192] NOT stored)
    //   csr     : 64K..64K+1M (src per edge)
    //   A       : +2MB        (Hs scaled hlin; cursor aliases A[0:32K] pre-gemm)
    //   B       : +2MB        (h1 float; later aliased by h2b bf16)
    char* ws = (char*)d_ws;
    int*   degdinv = (int*)ws;
    float* dinv    = (float*)ws;
    int*   off     = (int*)(ws + 32 * 1024);
    int*   csr     = (int*)(ws + 64 * 1024);
    float* A       = (float*)(ws + 64 * 1024 + 1024 * 1024);
    int*   cursor  = (int*)A;  // dead before k_gemm writes A
    float* B       = (float*)(ws + 64 * 1024 + 3 * 1024 * 1024);
    __hip_bfloat16* h2b = (__hip_bfloat16*)B;  // B (h1) dead after gemm2

    const int NB = N_NODES / 256;   // 32
    const int EB = (E + 255) / 256; // 1024
    const int GB = N_NODES / 4;     // 2048 blocks for gather

    // graph preprocessing (once; reused by both layers)
    k_deg_init<<<NB, 256, 0, stream>>>(degdinv);
    k_deg_count<<<EB, 256, 0, stream>>>(dst, degdinv, E);
    k_scan<<<1, 1024, 0, stream>>>(degdinv, off, cursor);      // reads int deg
    k_dinv_inplace<<<NB, 256, 0, stream>>>(degdinv);           // now float rsqrt
    k_fill<<<EB, 256, 0, stream>>>(src, dst, cursor, csr, E);

    // layer 1: A = dinv .* (x @ W1) ; h1 = relu(dinv .* gather-sum(A) + b1)
    k_gemm<<<N_NODES / 16, 256, 0, stream>>>(x, W1, dinv, A, 128);
    k_gather<0><<<GB, 256, 0, stream>>>(A, dinv, off, csr, b1, B, nullptr, E);

    // layer 2: A = dinv .* (h1 @ W2) ; h2 = relu(dinv .* gather-sum(A) + b2) -> bf16
    k_gemm<<<N_NODES / 16, 256, 0, stream>>>(B, W2, dinv, A, 64);
    k_gather<1><<<GB, 256, 0, stream>>>(A, dinv, off, csr, b2, nullptr, h2b, E);

    // sim = sigmoid(h2 @ h2^T)
    dim3 g(N_NODES / 128, N_NODES / 128);
    k_sim<<<g, 256, 0, stream>>>((const short*)h2b, (float*)d_out);
}

// Round 10
// 413.310 us; speedup vs baseline: 2.0024x; 1.0068x over previous
//
#include <hip/hip_runtime.h>
#include <hip/hip_bf16.h>

#define N_NODES 8192
#define HID 64

typedef __attribute__((ext_vector_type(8))) short bf16x8;
typedef __attribute__((ext_vector_type(4))) float f32x4;

// ---------------- degree / normalization ----------------
// deg (int) and dinv (float) SHARE one 32KB buffer; k_dinv_inplace converts
// int->rsqrt(float) in place, and runs AFTER k_scan (which needs integer deg).
__global__ void k_deg_init(int* __restrict__ deg) {
    int i = blockIdx.x * 256 + threadIdx.x;
    deg[i] = 1;  // self loop
}

__global__ void k_deg_count(const int* __restrict__ dst, int* __restrict__ deg, int E) {
    int e = blockIdx.x * 256 + threadIdx.x;
    if (e < E) atomicAdd(&deg[dst[e]], 1);
}

__global__ void k_dinv_inplace(int* __restrict__ degdinv) {
    int i = blockIdx.x * 256 + threadIdx.x;
    float d = (float)degdinv[i];
    ((float*)degdinv)[i] = rsqrtf(d);
}

// ---------------- CSR build (once; reused by both layers) ----------------
// exclusive scan of edge-degrees (deg-1) over 8192 nodes, single block.
// off has EXACTLY 8192 ints; off[8192] is NOT stored (gather uses E for the
// last node) -- storing it was the R7 crash (overflowed into cursor[0]).
__global__ void __launch_bounds__(1024) k_scan(const int* __restrict__ deg,
                                               int* __restrict__ off,
                                               int* __restrict__ cursor) {
    __shared__ int s[1024];
    const int t = threadIdx.x;
    int v[8];
    int sum = 0;
    const int base = t * 8;
#pragma unroll
    for (int j = 0; j < 8; ++j) { v[j] = deg[base + j] - 1; sum += v[j]; }
    s[t] = sum;
    __syncthreads();
    for (int d = 1; d < 1024; d <<= 1) {
        int x = (t >= d) ? s[t - d] : 0;
        __syncthreads();
        s[t] += x;
        __syncthreads();
    }
    int ex = s[t] - sum;  // exclusive prefix
#pragma unroll
    for (int j = 0; j < 8; ++j) {
        off[base + j] = ex;
        cursor[base + j] = ex;
        ex += v[j];
    }
}

// bucket edges by dst; store src only (norm factored into gemm epilogue/gather)
__global__ void k_fill(const int* __restrict__ src, const int* __restrict__ dst,
                       int* __restrict__ cursor, int* __restrict__ csr, int E) {
    int e = blockIdx.x * 256 + threadIdx.x;
    if (e >= E) return;
    int pos = atomicAdd(&cursor[dst[e]], 1);
    csr[pos] = src[e];
}

// ---------------- dense linear + row scale:  Y[r] = dinv[r] * (X @ W)[r] ----
__global__ void __launch_bounds__(256) k_gemm(const float* __restrict__ X,
                                              const float* __restrict__ W,
                                              const float* __restrict__ dinv,
                                              float* __restrict__ Y, int K) {
    const int col  = threadIdx.x & 63;
    const int wv   = threadIdx.x >> 6;            // wave id 0..3
    const int row0 = blockIdx.x * 16 + wv * 4;    // 4 rows per thread
    float a0 = 0.f, a1 = 0.f, a2 = 0.f, a3 = 0.f;
    const float* x0 = X + (size_t)row0 * K;
    for (int k = 0; k < K; ++k) {
        float w = W[k * 64 + col];
        a0 += x0[k] * w;
        a1 += x0[K + k] * w;
        a2 += x0[2 * K + k] * w;
        a3 += x0[3 * K + k] * w;
    }
    size_t o = (size_t)row0 * 64 + col;
    Y[o]       = a0 * dinv[row0];
    Y[o + 64]  = a1 * dinv[row0 + 1];
    Y[o + 128] = a2 * dinv[row0 + 2];
    Y[o + 192] = a3 * dinv[row0 + 3];
}

// ---------------- gather aggregation + bias + relu (fused) ----------------
// Hs[r] = dinv[r]*(XW)[r] already scaled. agg[d] = dinv[d]*(Hs[d] + sum Hs[src]).
// one wave per node, lane = channel. MODE 0: write float. MODE 1: write bf16.
template <int MODE>
__global__ void __launch_bounds__(256) k_gather(const float* __restrict__ Hs,
                                                const float* __restrict__ dinv,
                                                const int* __restrict__ off,
                                                const int* __restrict__ csr,
                                                const float* __restrict__ bias,
                                                float* __restrict__ outf,
                                                __hip_bfloat16* __restrict__ outb,
                                                int E) {
    const int node = blockIdx.x * 4 + (threadIdx.x >> 6);
    const int lane = threadIdx.x & 63;
    float acc = Hs[(size_t)node * 64 + lane];  // self-loop term (pre-scaled)
    int k = off[node];
    const int end = (node == N_NODES - 1) ? E : off[node + 1];
    for (; k + 1 < end; k += 2) {  // unroll-2: two independent load chains
        int s0 = csr[k];
        int s1 = csr[k + 1];
        float h0 = Hs[(size_t)s0 * 64 + lane];
        float h1 = Hs[(size_t)s1 * 64 + lane];
        acc += h0;
        acc += h1;
    }
    if (k < end) acc += Hs[(size_t)csr[k] * 64 + lane];
    float v = dinv[node] * acc + bias[lane];
    v = v > 0.f ? v : 0.f;
    if (MODE == 0) outf[(size_t)node * 64 + lane] = v;
    else           outb[(size_t)node * 64 + lane] = __float2bfloat16(v);
}

// ---------------- sim = sigmoid(h @ h^T), bf16 MFMA ----------------
// block = 256 thr (4 waves), block tile 128x128, wave tile 64x64 (4x4 MFMA tiles).
// Output staged through LDS (two 64-row halves) so global stores are f32x4
// with 512B-contiguous row runs (vs the raw C-layout's scattered 64B segments).
__global__ void __launch_bounds__(256) k_sim(const short* __restrict__ Hb,
                                             float* __restrict__ out) {
    __shared__ float lds[64][132];  // pad 132: row stride 528B, 16B-aligned, 2-way bank alias only
    const int lane = threadIdx.x & 63;
    const int wv   = threadIdx.x >> 6;
    const int rh   = wv >> 1;       // row half of this wave (0/1)
    const int ch   = wv & 1;        // col half of this wave (0/1)
    const int br = blockIdx.y * 128 + rh * 64;
    const int bc = blockIdx.x * 128 + ch * 64;
    const int lr = lane & 15;   // row/col within 16
    const int kg = lane >> 4;   // k-group (8 contiguous bf16)

    bf16x8 a[4][2], b[4][2];
#pragma unroll
    for (int t = 0; t < 4; ++t)
#pragma unroll
        for (int kk = 0; kk < 2; ++kk) {
            a[t][kk] = *(const bf16x8*)(Hb + (size_t)(br + t * 16 + lr) * 64 + kk * 32 + kg * 8);
            b[t][kk] = *(const bf16x8*)(Hb + (size_t)(bc + t * 16 + lr) * 64 + kk * 32 + kg * 8);
        }

    f32x4 acc[4][4] = {};
#pragma unroll
    for (int i = 0; i < 4; ++i)
#pragma unroll
        for (int j = 0; j < 4; ++j) {
            acc[i][j] = __builtin_amdgcn_mfma_f32_16x16x32_bf16(a[i][0], b[j][0], acc[i][j], 0, 0, 0);
            acc[i][j] = __builtin_amdgcn_mfma_f32_16x16x32_bf16(a[i][1], b[j][1], acc[i][j], 0, 0, 0);
        }

    // sigmoid in-register
#pragma unroll
    for (int i = 0; i < 4; ++i)
#pragma unroll
        for (int j = 0; j < 4; ++j)
#pragma unroll
            for (int r = 0; r < 4; ++r)
                acc[i][j][r] = 1.0f / (1.0f + __expf(-acc[i][j][r]));

    // stage + write, one 64-row half at a time
    const int orow = threadIdx.x >> 5;   // 0..7
    const int oq   = threadIdx.x & 31;   // 0..31 (f32x4 index within 128-col row)
    const size_t ocol = (size_t)blockIdx.x * 128 + oq * 4;
#pragma unroll
    for (int h = 0; h < 2; ++h) {
        if (rh == h) {
#pragma unroll
            for (int i = 0; i < 4; ++i)
#pragma unroll
                for (int j = 0; j < 4; ++j)
#pragma unroll
                    for (int r = 0; r < 4; ++r)
                        lds[i * 16 + kg * 4 + r][ch * 64 + j * 16 + lr] = acc[i][j][r];
        }
        __syncthreads();
#pragma unroll
        for (int p = 0; p < 8; ++p) {
            int rr = p * 8 + orow;
            f32x4 v = *(const f32x4*)&lds[rr][oq * 4];
            *(f32x4*)&out[(size_t)(blockIdx.y * 128 + h * 64 + rr) * N_NODES + ocol] = v;
        }
        __syncthreads();
    }
}

extern "C" void kernel_launch(void* const* d_in, const int* in_sizes, int n_in,
                              void* d_out, int out_size, void* d_ws, size_t ws_size,
                              hipStream_t stream) {
    const float* x  = (const float*)d_in[0];
    const int*   ei = (const int*)d_in[1];
    const float* W1 = (const float*)d_in[2];
    const float* b1 = (const float*)d_in[3];
    const float* W2 = (const float*)d_in[4];
    const float* b2 = (const float*)d_in[5];
    const int E = in_sizes[1] / 2;
    const int* src = ei;
    const int* dst = ei + E;

    // Workspace layout -- total 64KB + 5MB = 5,308,416 B.
    //   degdinv : 0..32K      (int deg, converted in-place to float rsqrt)
    //   off     : 32K..64K    (8192 ints exactly; off[8192] NOT stored)
    //   csr     : 64K..64K+1M (src per edge)
    //   A       : +2MB        (Hs scaled hlin; cursor aliases A[0:32K] pre-gemm)
    //   B       : +2MB        (h1 float; later aliased by h2b bf16)
    char* ws = (char*)d_ws;
    int*   degdinv = (int*)ws;
    float* dinv    = (float*)ws;
    int*   off     = (int*)(ws + 32 * 1024);
    int*   csr     = (int*)(ws + 64 * 1024);
    float* A       = (float*)(ws + 64 * 1024 + 1024 * 1024);
    int*   cursor  = (int*)A;  // dead before k_gemm writes A
    float* B       = (float*)(ws + 64 * 1024 + 3 * 1024 * 1024);
    __hip_bfloat16* h2b = (__hip_bfloat16*)B;  // B (h1) dead after gemm2

    const int NB = N_NODES / 256;   // 32
    const int EB = (E + 255) / 256; // 1024
    const int GB = N_NODES / 4;     // 2048 blocks for gather

    // graph preprocessing (once; reused by both layers)
    k_deg_init<<<NB, 256, 0, stream>>>(degdinv);
    k_deg_count<<<EB, 256, 0, stream>>>(dst, degdinv, E);
    k_scan<<<1, 1024, 0, stream>>>(degdinv, off, cursor);      // reads int deg
    k_dinv_inplace<<<NB, 256, 0, stream>>>(degdinv);           // now float rsqrt
    k_fill<<<EB, 256, 0, stream>>>(src, dst, cursor, csr, E);

    // layer 1: A = dinv .* (x @ W1) ; h1 = relu(dinv .* gather-sum(A) + b1)
    k_gemm<<<N_NODES / 16, 256, 0, stream>>>(x, W1, dinv, A, 128);
    k_gather<0><<<GB, 256, 0, stream>>>(A, dinv, off, csr, b1, B, nullptr, E);

    // layer 2: A = dinv .* (h1 @ W2) ; h2 = relu(dinv .* gather-sum(A) + b2) -> bf16
    k_gemm<<<N_NODES / 16, 256, 0, stream>>>(B, W2, dinv, A, 64);
    k_gather<1><<<GB, 256, 0, stream>>>(A, dinv, off, csr, b2, nullptr, h2b, E);

    // sim = sigmoid(h2 @ h2^T)
    dim3 g(N_NODES / 128, N_NODES / 128);
    k_sim<<<g, 256, 0, stream>>>((const short*)h2b, (float*)d_out);
}

// Round 11
// 391.727 us; speedup vs baseline: 2.1127x; 1.0551x over previous
//
#include <hip/hip_runtime.h>
#include <hip/hip_bf16.h>

#define N_NODES 8192
#define HID 64

typedef __attribute__((ext_vector_type(8))) short bf16x8;
typedef __attribute__((ext_vector_type(4))) float f32x4;

// ---------------- degree count (deg buffer memset to 0 by host code) -------
__global__ void k_deg_count(const int* __restrict__ dst, int* __restrict__ deg, int E) {
    int e = blockIdx.x * 256 + threadIdx.x;
    if (e < E) atomicAdd(&deg[dst[e]], 1);
}

// ---------------- CSR offsets + dinv (fused) ------------------------------
// deg[i] = edge count (no self loop). Exclusive scan over 8192 nodes, one
// block. Also converts deg -> dinv = rsqrt(deg+1) in place (self loop +1).
// off has EXACTLY 8192 ints; off[8192] NOT stored (gather uses E for last
// node) -- storing it was the R7 crash (overflowed into cursor[0]).
__global__ void __launch_bounds__(1024) k_scan(int* __restrict__ degdinv,
                                               int* __restrict__ off,
                                               int* __restrict__ cursor) {
    __shared__ int s[1024];
    const int t = threadIdx.x;
    int v[8];
    int sum = 0;
    const int base = t * 8;
#pragma unroll
    for (int j = 0; j < 8; ++j) { v[j] = degdinv[base + j]; sum += v[j]; }
    s[t] = sum;
    __syncthreads();
    for (int d = 1; d < 1024; d <<= 1) {
        int x = (t >= d) ? s[t - d] : 0;
        __syncthreads();
        s[t] += x;
        __syncthreads();
    }
    int ex = s[t] - sum;  // exclusive prefix
#pragma unroll
    for (int j = 0; j < 8; ++j) {
        off[base + j] = ex;
        cursor[base + j] = ex;
        ex += v[j];
        ((float*)degdinv)[base + j] = rsqrtf((float)(v[j] + 1));  // dinv in place
    }
}

// bucket edges by dst; store src only (norm factored into gemm epilogue/gather)
__global__ void k_fill(const int* __restrict__ src, const int* __restrict__ dst,
                       int* __restrict__ cursor, int* __restrict__ csr, int E) {
    int e = blockIdx.x * 256 + threadIdx.x;
    if (e >= E) return;
    int pos = atomicAdd(&cursor[dst[e]], 1);
    csr[pos] = src[e];
}

// ---------------- dense linear + row scale:  Y[r] = dinv[r] * (X @ W)[r] ----
__global__ void __launch_bounds__(256) k_gemm(const float* __restrict__ X,
                                              const float* __restrict__ W,
                                              const float* __restrict__ dinv,
                                              float* __restrict__ Y, int K) {
    const int col  = threadIdx.x & 63;
    const int wv   = threadIdx.x >> 6;            // wave id 0..3
    const int row0 = blockIdx.x * 16 + wv * 4;    // 4 rows per thread
    float a0 = 0.f, a1 = 0.f, a2 = 0.f, a3 = 0.f;
    const float* x0 = X + (size_t)row0 * K;
    for (int k = 0; k < K; ++k) {
        float w = W[k * 64 + col];
        a0 += x0[k] * w;
        a1 += x0[K + k] * w;
        a2 += x0[2 * K + k] * w;
        a3 += x0[3 * K + k] * w;
    }
    size_t o = (size_t)row0 * 64 + col;
    Y[o]       = a0 * dinv[row0];
    Y[o + 64]  = a1 * dinv[row0 + 1];
    Y[o + 128] = a2 * dinv[row0 + 2];
    Y[o + 192] = a3 * dinv[row0 + 3];
}

// ---------------- layer-1 gather + bias/relu + FUSED gemm2 -----------------
// Per node (one wave): h1[lane] = relu(dinv*gathersum(Hs1)+b1), held in
// registers across the wave (lane = channel). Then the row of h1 @ W2 is
// computed in-register via 64 __shfl broadcasts (no h1 materialization, no
// separate gemm2 kernel). Output: Hs2[r][c] = dinv[r] * (h1 @ W2)[r][c].
__global__ void __launch_bounds__(256) k_gather_gemm2(const float* __restrict__ Hs1,
                                                      const float* __restrict__ dinv,
                                                      const int* __restrict__ off,
                                                      const int* __restrict__ csr,
                                                      const float* __restrict__ b1,
                                                      const float* __restrict__ W2,
                                                      float* __restrict__ Hs2,
                                                      int E) {
    const int node = blockIdx.x * 4 + (threadIdx.x >> 6);
    const int lane = threadIdx.x & 63;
    float acc = Hs1[(size_t)node * 64 + lane];  // self-loop term (pre-scaled)
    int k = off[node];
    const int end = (node == N_NODES - 1) ? E : off[node + 1];
    for (; k + 1 < end; k += 2) {
        int s0 = csr[k];
        int s1 = csr[k + 1];
        float h0 = Hs1[(size_t)s0 * 64 + lane];
        float h1 = Hs1[(size_t)s1 * 64 + lane];
        acc += h0;
        acc += h1;
    }
    if (k < end) acc += Hs1[(size_t)csr[k] * 64 + lane];
    const float di = dinv[node];
    float h1v = di * acc + b1[lane];
    h1v = h1v > 0.f ? h1v : 0.f;

    // gemm2 row: o[c] = sum_k h1[k] * W2[k][c], c = lane
    float o = 0.f;
#pragma unroll
    for (int kk = 0; kk < HID; ++kk) {
        float hk = __shfl(h1v, kk, 64);
        o += hk * W2[kk * 64 + lane];
    }
    Hs2[(size_t)node * 64 + lane] = o * di;
}

// ---------------- layer-2 gather + bias/relu -> bf16 -----------------------
__global__ void __launch_bounds__(256) k_gather2(const float* __restrict__ Hs,
                                                 const float* __restrict__ dinv,
                                                 const int* __restrict__ off,
                                                 const int* __restrict__ csr,
                                                 const float* __restrict__ bias,
                                                 __hip_bfloat16* __restrict__ outb,
                                                 int E) {
    const int node = blockIdx.x * 4 + (threadIdx.x >> 6);
    const int lane = threadIdx.x & 63;
    float acc = Hs[(size_t)node * 64 + lane];
    int k = off[node];
    const int end = (node == N_NODES - 1) ? E : off[node + 1];
    for (; k + 1 < end; k += 2) {
        int s0 = csr[k];
        int s1 = csr[k + 1];
        float h0 = Hs[(size_t)s0 * 64 + lane];
        float h1 = Hs[(size_t)s1 * 64 + lane];
        acc += h0;
        acc += h1;
    }
    if (k < end) acc += Hs[(size_t)csr[k] * 64 + lane];
    float v = dinv[node] * acc + bias[lane];
    v = v > 0.f ? v : 0.f;
    outb[(size_t)node * 64 + lane] = __float2bfloat16(v);
}

// ---------------- sim = sigmoid(h @ h^T), bf16 MFMA ----------------
// block = 256 thr (4 waves), block tile 128x128, wave tile 64x64 (4x4 MFMA
// tiles). Output staged through LDS -> f32x4 stores (measured neutral vs raw
// C-layout stores in R8/R10 A/B; kept -- both at the store floor).
__global__ void __launch_bounds__(256) k_sim(const short* __restrict__ Hb,
                                             float* __restrict__ out) {
    __shared__ float lds[64][132];
    const int lane = threadIdx.x & 63;
    const int wv   = threadIdx.x >> 6;
    const int rh   = wv >> 1;
    const int ch   = wv & 1;
    const int br = blockIdx.y * 128 + rh * 64;
    const int bc = blockIdx.x * 128 + ch * 64;
    const int lr = lane & 15;
    const int kg = lane >> 4;

    bf16x8 a[4][2], b[4][2];
#pragma unroll
    for (int t = 0; t < 4; ++t)
#pragma unroll
        for (int kk = 0; kk < 2; ++kk) {
            a[t][kk] = *(const bf16x8*)(Hb + (size_t)(br + t * 16 + lr) * 64 + kk * 32 + kg * 8);
            b[t][kk] = *(const bf16x8*)(Hb + (size_t)(bc + t * 16 + lr) * 64 + kk * 32 + kg * 8);
        }

    f32x4 acc[4][4] = {};
#pragma unroll
    for (int i = 0; i < 4; ++i)
#pragma unroll
        for (int j = 0; j < 4; ++j) {
            acc[i][j] = __builtin_amdgcn_mfma_f32_16x16x32_bf16(a[i][0], b[j][0], acc[i][j], 0, 0, 0);
            acc[i][j] = __builtin_amdgcn_mfma_f32_16x16x32_bf16(a[i][1], b[j][1], acc[i][j], 0, 0, 0);
        }

#pragma unroll
    for (int i = 0; i < 4; ++i)
#pragma unroll
        for (int j = 0; j < 4; ++j)
#pragma unroll
            for (int r = 0; r < 4; ++r)
                acc[i][j][r] = 1.0f / (1.0f + __expf(-acc[i][j][r]));

    const int orow = threadIdx.x >> 5;
    const int oq   = threadIdx.x & 31;
    const size_t ocol = (size_t)blockIdx.x * 128 + oq * 4;
#pragma unroll
    for (int h = 0; h < 2; ++h) {
        if (rh == h) {
#pragma unroll
            for (int i = 0; i < 4; ++i)
#pragma unroll
                for (int j = 0; j < 4; ++j)
#pragma unroll
                    for (int r = 0; r < 4; ++r)
                        lds[i * 16 + kg * 4 + r][ch * 64 + j * 16 + lr] = acc[i][j][r];
        }
        __syncthreads();
#pragma unroll
        for (int p = 0; p < 8; ++p) {
            int rr = p * 8 + orow;
            f32x4 v = *(const f32x4*)&lds[rr][oq * 4];
            *(f32x4*)&out[(size_t)(blockIdx.y * 128 + h * 64 + rr) * N_NODES + ocol] = v;
        }
        __syncthreads();
    }
}

extern "C" void kernel_launch(void* const* d_in, const int* in_sizes, int n_in,
                              void* d_out, int out_size, void* d_ws, size_t ws_size,
                              hipStream_t stream) {
    const float* x  = (const float*)d_in[0];
    const int*   ei = (const int*)d_in[1];
    const float* W1 = (const float*)d_in[2];
    const float* b1 = (const float*)d_in[3];
    const float* W2 = (const float*)d_in[4];
    const float* b2 = (const float*)d_in[5];
    const int E = in_sizes[1] / 2;
    const int* src = ei;
    const int* dst = ei + E;

    // Workspace layout -- total 64KB + 5MB.
    //   degdinv : 0..32K       (int edge-deg -> float rsqrt(deg+1) in k_scan)
    //   off     : 32K..64K     (8192 ints exactly)
    //   csr     : 64K..64K+1M  (src per edge)
    //   A       : +2MB         (Hs1; cursor aliases A[0:32K] pre-gemm1;
    //                           h2b bf16 aliases A after gather_gemm2)
    //   B       : +2MB         (Hs2 from fused gemm2)
    char* ws = (char*)d_ws;
    int*   degdinv = (int*)ws;
    float* dinv    = (float*)ws;
    int*   off     = (int*)(ws + 32 * 1024);
    int*   csr     = (int*)(ws + 64 * 1024);
    float* A       = (float*)(ws + 64 * 1024 + 1024 * 1024);
    int*   cursor  = (int*)A;                  // dead before gemm1 writes A
    float* B       = (float*)(ws + 64 * 1024 + 3 * 1024 * 1024);
    __hip_bfloat16* h2b = (__hip_bfloat16*)A;  // A (Hs1) dead after gather_gemm2

    const int EB = (E + 255) / 256; // 1024
    const int GB = N_NODES / 4;     // 2048 blocks for gathers

    // graph preprocessing (once; reused by both layers)
    hipMemsetAsync(degdinv, 0, N_NODES * sizeof(int), stream);
    k_deg_count<<<EB, 256, 0, stream>>>(dst, degdinv, E);
    k_scan<<<1, 1024, 0, stream>>>(degdinv, off, cursor);   // offsets + dinv
    k_fill<<<EB, 256, 0, stream>>>(src, dst, cursor, csr, E);

    // layer 1 + fused layer-2 linear:
    //   A = dinv .* (x @ W1);  B = dinv .* (relu(dinv.*gather(A)+b1) @ W2)
    k_gemm<<<N_NODES / 16, 256, 0, stream>>>(x, W1, dinv, A, 128);
    k_gather_gemm2<<<GB, 256, 0, stream>>>(A, dinv, off, csr, b1, W2, B, E);

    // layer 2 aggregation: h2 = relu(dinv .* gather(B) + b2) -> bf16 (at A)
    k_gather2<<<GB, 256, 0, stream>>>(B, dinv, off, csr, b2, h2b, E);

    // sim = sigmoid(h2 @ h2^T)
    dim3 g(N_NODES / 128, N_NODES / 128);
    k_sim<<<g, 256, 0, stream>>>((const short*)h2b, (float*)d_out);
}